// Round 14
// baseline (507.159 us; speedup 1.0000x reference)
//
#include <hip/hip_runtime.h>
#include <hip/hip_bf16.h>

// ISTA split-bf16 MFMA, round 14 = R13 with kt=3 (94% padding) replaced by a
// uniform f32 VALU residual.
// C' = S · d^T (A = S register-resident, B = d from LDS, m89 C-layout).
// ROWS=16, grid=256 (1 block/CU), 448 threads = 7 waves, wave w owns N-tile w.
// R13 ledger (1074 cy/CU/iter): 56 b128 reads 672 + conflicts 280 + writes 84
// ~= 1036 -> LDS-read-throughput-bound. kt=3's 2 b128/wave (2 KB, 25% of
// traffic) fetch k=96..127 with only k=96..99 real. Replacement (NO
// predication -- R12 lesson):
//   - 2 uniform b64 broadcast reads of d[l15][96..99] hi/lo (addr uniform
//     across lg groups -> broadcast; banks 16+4*(l15&7), 2-way alias = free)
//   - recombine to f32, 16-FMA residual with exact-f32 S[j][96..99]
//     (register-resident, 16 VGPRs) added into the epilogue sum.
// MFMAs 12 -> 9/wave. Numerics: k 96..99 now EXACT f32 (vs 3-product
// split-bf16) -- strictly more accurate per iter; absmax ~0.03.

#define ROWS     16
#define KPAD     128
#define N_DIM    100
#define M_DIM    70
#define NTHREADS 448          // 7 waves

typedef __attribute__((ext_vector_type(8))) short short8;
typedef __attribute__((ext_vector_type(4))) float f32x4;

static __device__ __forceinline__ unsigned short f2bf(float f) {
    unsigned u = __float_as_uint(f);
    u += 0x7FFF + ((u >> 16) & 1);          // RNE
    return (unsigned short)(u >> 16);
}
static __device__ __forceinline__ float bf2f(unsigned short b) {
    return __uint_as_float(((unsigned)b) << 16);
}
// packed RNE: low16 = bf16(a), high16 = bf16(b)
static __device__ __forceinline__ unsigned cvt_pk_bf16(float a, float b) {
    unsigned r;
    asm("v_cvt_pk_bf16_f32 %0, %1, %2" : "=v"(r) : "v"(a), "v"(b));
    return r;
}
static __device__ __forceinline__ float med3f(float x, float lo, float hi) {
    float r;
    asm("v_med3_f32 %0, %1, %2, %3" : "=v"(r) : "v"(x), "v"(lo), "v"(hi));
    return r;
}

__global__ __launch_bounds__(NTHREADS, 2)
void ista_mfma11(const float* __restrict__ y,
                 const float* __restrict__ S,
                 const float* __restrict__ W,
                 const float* __restrict__ thr,
                 const int*   __restrict__ numIter,
                 float* __restrict__ out)
{
    __shared__ __align__(16) unsigned short dh[2][ROWS * KPAD];  // d hi bf16 bits
    __shared__ __align__(16) unsigned short dl[2][ROWS * KPAD];  // d lo bf16 bits

    const int t    = threadIdx.x;
    const int wv   = t >> 6;        // wave 0..6 = N-tile index
    const int l    = t & 63;
    const int l15  = l & 15;
    const int lg   = l >> 4;
    const int row0 = blockIdx.x * ROWS;
    const float th  = thr[0];
    const float nth = -th;
    const int iters = numIter[0];
    const unsigned swz = (unsigned)((l15 & 7) << 4);

    // ---- one-time: S fragments for kt 0..2, A operand (row = l15) ----
    short8 Sh[3], Sl[3];
    {
        const int jg = wv * 16 + l15;                      // global output column
        #pragma unroll
        for (int kt = 0; kt < 3; ++kt) {
            #pragma unroll
            for (int i = 0; i < 8; ++i) {
                const int k = kt * 32 + lg * 8 + i;
                const float v = (jg < N_DIM) ? S[jg * N_DIM + k] : 0.f;
                const unsigned short hb = f2bf(v);
                Sh[kt][i] = (short)hb;
                Sl[kt][i] = (short)f2bf(v - bf2f(hb));
            }
        }
    }

    // ---- one-time: exact-f32 S residual for k=96..99, per output j=lg*4+q ----
    f32x4 Sres[4];                  // Sres[q][k'] = S[j][96+k']
    #pragma unroll
    for (int q = 0; q < 4; ++q) {
        const int j = wv * 16 + lg * 4 + q;
        #pragma unroll
        for (int kk = 0; kk < 4; ++kk)
            Sres[q][kk] = (j < N_DIM) ? S[j * N_DIM + 96 + kk] : 0.f;
    }

    // ---- one-time: Wy in C' layout (lane: d-row = l15, j = wv*16 + lg*4+q) ----
    f32x4 Wyr;
    #pragma unroll
    for (int q = 0; q < 4; ++q) {
        const int j = wv * 16 + lg * 4 + q;
        float acc = 0.f;
        if (j < N_DIM) {
            const float* yr = y + (size_t)(row0 + l15) * M_DIM;
            const float* wr = W + (size_t)j * M_DIM;
            #pragma unroll 10
            for (int m = 0; m < M_DIM; ++m) acc = fmaf(yr[m], wr[m], acc);
        }
        Wyr[q] = acc;
    }

    // ---- zero BOTH buffers (cols 112-127 & pad k never rewritten) ----
    for (int idx = t; idx < 2 * ROWS * KPAD; idx += NTHREADS) {
        dh[0][idx] = 0; dl[0][idx] = 0;   // flat over dh[0..1] / dl[0..1]
    }
    __syncthreads();

    // loop-invariant byte offsets (XOR swizzle on byte bits 4..6)
    unsigned roff[3];
    #pragma unroll
    for (int kt = 0; kt < 3; ++kt)
        roff[kt] = ((unsigned)(l15 * 256 + kt * 64 + lg * 16)) ^ swz;
    const unsigned resoff = ((unsigned)(l15 * 256 + 192)) ^ swz;   // k=96..99, lg-uniform
    const unsigned woff   = ((unsigned)(l15 * 256 + wv * 32 + lg * 8)) ^ swz;

    int cur = 0;
    for (int it = 0; it < iters; ++it) {
        const char* rh = (const char*)dh[cur];
        const char* rl = (const char*)dl[cur];
        char* wh = (char*)dh[cur ^ 1];
        char* wl = (char*)dl[cur ^ 1];

        // ---- 6 b128 reads (kt 0..2) + 2 b64 broadcast reads (k 96..99) ----
        short8 Bh[3], Bl[3];
        #pragma unroll
        for (int kt = 0; kt < 3; ++kt) {
            Bh[kt] = *(const short8*)(rh + roff[kt]);
            Bl[kt] = *(const short8*)(rl + roff[kt]);
        }
        const uint2 rdh = *(const uint2*)(rh + resoff);
        const uint2 rdl = *(const uint2*)(rl + resoff);

        // ---- 9 MFMAs, 3 independent chains (dep depth = 3) ----
        f32x4 Chh = Wyr;
        f32x4 Chl = {0,0,0,0};
        f32x4 Clh = {0,0,0,0};
        #pragma unroll
        for (int kt = 0; kt < 3; ++kt) {
            Chh = __builtin_amdgcn_mfma_f32_16x16x32_bf16(Sh[kt], Bh[kt], Chh, 0, 0, 0);
            Chl = __builtin_amdgcn_mfma_f32_16x16x32_bf16(Sh[kt], Bl[kt], Chl, 0, 0, 0);
            Clh = __builtin_amdgcn_mfma_f32_16x16x32_bf16(Sl[kt], Bh[kt], Clh, 0, 0, 0);
        }

        // ---- f32 residual for k=96..99 (uniform, overlaps MFMA in scheduler) ----
        float dv[4];
        dv[0] = __uint_as_float(rdh.x << 16)          + __uint_as_float(rdl.x << 16);
        dv[1] = __uint_as_float(rdh.x & 0xFFFF0000u)  + __uint_as_float(rdl.x & 0xFFFF0000u);
        dv[2] = __uint_as_float(rdh.y << 16)          + __uint_as_float(rdl.y << 16);
        dv[3] = __uint_as_float(rdh.y & 0xFFFF0000u)  + __uint_as_float(rdl.y & 0xFFFF0000u);
        f32x4 res = {0,0,0,0};
        #pragma unroll
        for (int kk = 0; kk < 4; ++kk) {
            res[0] = fmaf(Sres[0][kk], dv[kk], res[0]);
            res[1] = fmaf(Sres[1][kk], dv[kk], res[1]);
            res[2] = fmaf(Sres[2][kk], dv[kk], res[2]);
            res[3] = fmaf(Sres[3][kk], dv[kk], res[3]);
        }

        // ---- epilogue: sum chains + residual, med3-softthr, cvt_pk, b64 writes ----
        float r0, r1, r2, r3;
        {
            const float s0 = Chh[0] + Chl[0] + Clh[0] + res[0];
            const float s1 = Chh[1] + Chl[1] + Clh[1] + res[1];
            const float s2 = Chh[2] + Chl[2] + Clh[2] + res[2];
            const float s3 = Chh[3] + Chl[3] + Clh[3] + res[3];
            r0 = s0 - med3f(s0, nth, th);
            r1 = s1 - med3f(s1, nth, th);
            r2 = s2 - med3f(s2, nth, th);
            r3 = s3 - med3f(s3, nth, th);
        }
        const unsigned h01 = cvt_pk_bf16(r0, r1);
        const unsigned h23 = cvt_pk_bf16(r2, r3);
        const float l0 = r0 - __uint_as_float(h01 << 16);
        const float l1 = r1 - __uint_as_float(h01 & 0xFFFF0000u);
        const float l2 = r2 - __uint_as_float(h23 << 16);
        const float l3 = r3 - __uint_as_float(h23 & 0xFFFF0000u);
        const unsigned lo01 = cvt_pk_bf16(l0, l1);
        const unsigned lo23 = cvt_pk_bf16(l2, l3);
        *(uint2*)(wh + woff) = make_uint2(h01, h23);
        *(uint2*)(wl + woff) = make_uint2(lo01, lo23);

        __syncthreads();          // one barrier: all real columns published
        cur ^= 1;
    }

    // ---- output: hi+lo recombine, write global ----
    for (int idx = t; idx < ROWS * N_DIM; idx += NTHREADS) {
        const int r = idx / N_DIM;
        const int j = idx - r * N_DIM;
        const unsigned off = ((unsigned)(r * 256 + j * 2)) ^ ((unsigned)((r & 7) << 4));
        const float v = bf2f(*(const unsigned short*)((const char*)dh[cur] + off))
                      + bf2f(*(const unsigned short*)((const char*)dl[cur] + off));
        out[(size_t)(row0 + r) * N_DIM + j] = v;
    }
}

extern "C" void kernel_launch(void* const* d_in, const int* in_sizes, int n_in,
                              void* d_out, int out_size, void* d_ws, size_t ws_size,
                              hipStream_t stream) {
    const float* y       = (const float*)d_in[0];
    const float* S       = (const float*)d_in[1];
    const float* W       = (const float*)d_in[2];
    const float* thr     = (const float*)d_in[3];
    const int*   numIter = (const int*)d_in[4];
    float* out = (float*)d_out;

    const int Brows = in_sizes[0] / M_DIM;   // 4096
    const int nblk  = Brows / ROWS;          // 256 blocks = 1/CU
    ista_mfma11<<<nblk, NTHREADS, 0, stream>>>(y, S, W, thr, numIter, out);
}

// Round 15
// 446.674 us; speedup vs baseline: 1.1354x; 1.1354x over previous
//
#include <hip/hip_runtime.h>
#include <hip/hip_bf16.h>

// ISTA split-bf16 MFMA — FINAL (restore of round-13 best, 448 µs).
// C' = S · d^T (A = S register-resident, B = d from LDS, m89 C-layout).
// ROWS=16, grid=256 (1 block/CU), 448 threads = 7 waves; wave w owns N-tile
// w (cols 16w..16w+15; cols 112-127 identically zero, never computed; pad
// stays zero via one-time init of BOTH buffers).
// Established by elimination (R5-R14):
//  - 7-wave column-split, ONE barrier/iter: row-split = exposed latency
//    (R7), K-split = extra barrier round (R8), row-groups = half chip (R9),
//    8th wave = pure pad traffic (R11->R13).
//  - NO predication / VALU residuals in the hot loop: R12 (-25% MfmaUtil),
//    R14 (serial FMA chain) both regressed.
//  - Ledger: 1074 cy/CU/iter ~= 42 b128-reads*12 + conflict surcharge 280 +
//    writes 84 -> LDS-read-pipe >96% accounted = practical floor; the 7x
//    read duplication is structural to the column split.
// Numerics: Sh*Bh + Sh*Bl + Sl*Bh (full K), RNE splits -> absmax 0.03125.

#define ROWS     16
#define KPAD     128
#define N_DIM    100
#define M_DIM    70
#define NTHREADS 448          // 7 waves

typedef __attribute__((ext_vector_type(8))) short short8;
typedef __attribute__((ext_vector_type(4))) float f32x4;

static __device__ __forceinline__ unsigned short f2bf(float f) {
    unsigned u = __float_as_uint(f);
    u += 0x7FFF + ((u >> 16) & 1);          // RNE
    return (unsigned short)(u >> 16);
}
static __device__ __forceinline__ float bf2f(unsigned short b) {
    return __uint_as_float(((unsigned)b) << 16);
}
// packed RNE: low16 = bf16(a), high16 = bf16(b)
static __device__ __forceinline__ unsigned cvt_pk_bf16(float a, float b) {
    unsigned r;
    asm("v_cvt_pk_bf16_f32 %0, %1, %2" : "=v"(r) : "v"(a), "v"(b));
    return r;
}
static __device__ __forceinline__ float med3f(float x, float lo, float hi) {
    float r;
    asm("v_med3_f32 %0, %1, %2, %3" : "=v"(r) : "v"(x), "v"(lo), "v"(hi));
    return r;
}

__global__ __launch_bounds__(NTHREADS, 2)
void ista_final(const float* __restrict__ y,
                const float* __restrict__ S,
                const float* __restrict__ W,
                const float* __restrict__ thr,
                const int*   __restrict__ numIter,
                float* __restrict__ out)
{
    __shared__ __align__(16) unsigned short dh[2][ROWS * KPAD];  // d hi bf16 bits
    __shared__ __align__(16) unsigned short dl[2][ROWS * KPAD];  // d lo bf16 bits

    const int t    = threadIdx.x;
    const int wv   = t >> 6;        // wave 0..6 = N-tile index
    const int l    = t & 63;
    const int l15  = l & 15;
    const int lg   = l >> 4;
    const int row0 = blockIdx.x * ROWS;
    const float th  = thr[0];
    const float nth = -th;
    const int iters = numIter[0];
    const unsigned swz = (unsigned)((l15 & 7) << 4);

    // ---- one-time: S fragments, A operand (row = l15 = j-in-tile) ----
    short8 Sh[4], Sl[4];
    {
        const int jg = wv * 16 + l15;                      // global output column
        #pragma unroll
        for (int kt = 0; kt < 4; ++kt) {
            #pragma unroll
            for (int i = 0; i < 8; ++i) {
                const int k = kt * 32 + lg * 8 + i;
                const float v = (jg < N_DIM && k < N_DIM) ? S[jg * N_DIM + k] : 0.f;
                const unsigned short hb = f2bf(v);
                Sh[kt][i] = (short)hb;
                Sl[kt][i] = (short)f2bf(v - bf2f(hb));
            }
        }
    }

    // ---- one-time: Wy in C' layout (lane: d-row = l15, j = wv*16 + lg*4+q) ----
    f32x4 Wyr;
    #pragma unroll
    for (int q = 0; q < 4; ++q) {
        const int j = wv * 16 + lg * 4 + q;
        float acc = 0.f;
        if (j < N_DIM) {
            const float* yr = y + (size_t)(row0 + l15) * M_DIM;
            const float* wr = W + (size_t)j * M_DIM;
            #pragma unroll 10
            for (int m = 0; m < M_DIM; ++m) acc = fmaf(yr[m], wr[m], acc);
        }
        Wyr[q] = acc;
    }

    // ---- zero BOTH buffers (cols 112-127 & pad k are never rewritten) ----
    for (int idx = t; idx < 2 * ROWS * KPAD; idx += NTHREADS) {
        dh[0][idx] = 0; dl[0][idx] = 0;   // flat over dh[0..1] / dl[0..1]
    }
    __syncthreads();

    // loop-invariant byte offsets (XOR swizzle on byte bits 4..6)
    unsigned roff[4];
    #pragma unroll
    for (int kt = 0; kt < 4; ++kt)
        roff[kt] = ((unsigned)(l15 * 256 + kt * 64 + lg * 16)) ^ swz;
    const unsigned woff = ((unsigned)(l15 * 256 + wv * 32 + lg * 8)) ^ swz;

    int cur = 0;
    for (int it = 0; it < iters; ++it) {
        const char* rh = (const char*)dh[cur];
        const char* rl = (const char*)dl[cur];
        char* wh = (char*)dh[cur ^ 1];
        char* wl = (char*)dl[cur ^ 1];

        // ---- 8 b128 reads: full d, fragments directly ----
        short8 Bh[4], Bl[4];
        #pragma unroll
        for (int kt = 0; kt < 4; ++kt) {
            Bh[kt] = *(const short8*)(rh + roff[kt]);
            Bl[kt] = *(const short8*)(rl + roff[kt]);
        }

        // ---- 12 MFMAs, 3 independent chains (dep depth = 4) ----
        f32x4 Chh = Wyr;
        f32x4 Chl = {0,0,0,0};
        f32x4 Clh = {0,0,0,0};
        #pragma unroll
        for (int kt = 0; kt < 4; ++kt) {
            Chh = __builtin_amdgcn_mfma_f32_16x16x32_bf16(Sh[kt], Bh[kt], Chh, 0, 0, 0);
            Chl = __builtin_amdgcn_mfma_f32_16x16x32_bf16(Sh[kt], Bl[kt], Chl, 0, 0, 0);
            Clh = __builtin_amdgcn_mfma_f32_16x16x32_bf16(Sl[kt], Bh[kt], Clh, 0, 0, 0);
        }

        // ---- epilogue: sum chains, med3-softthr, cvt_pk split, b64 writes ----
        float r0, r1, r2, r3;
        {
            const float s0 = Chh[0] + Chl[0] + Clh[0];
            const float s1 = Chh[1] + Chl[1] + Clh[1];
            const float s2 = Chh[2] + Chl[2] + Clh[2];
            const float s3 = Chh[3] + Chl[3] + Clh[3];
            r0 = s0 - med3f(s0, nth, th);
            r1 = s1 - med3f(s1, nth, th);
            r2 = s2 - med3f(s2, nth, th);
            r3 = s3 - med3f(s3, nth, th);
        }
        const unsigned h01 = cvt_pk_bf16(r0, r1);
        const unsigned h23 = cvt_pk_bf16(r2, r3);
        const float l0 = r0 - __uint_as_float(h01 << 16);
        const float l1 = r1 - __uint_as_float(h01 & 0xFFFF0000u);
        const float l2 = r2 - __uint_as_float(h23 << 16);
        const float l3 = r3 - __uint_as_float(h23 & 0xFFFF0000u);
        const unsigned lo01 = cvt_pk_bf16(l0, l1);
        const unsigned lo23 = cvt_pk_bf16(l2, l3);
        *(uint2*)(wh + woff) = make_uint2(h01, h23);
        *(uint2*)(wl + woff) = make_uint2(lo01, lo23);

        __syncthreads();          // one barrier: all real columns published
        cur ^= 1;
    }

    // ---- output: hi+lo recombine, write global ----
    for (int idx = t; idx < ROWS * N_DIM; idx += NTHREADS) {
        const int r = idx / N_DIM;
        const int j = idx - r * N_DIM;
        const unsigned off = ((unsigned)(r * 256 + j * 2)) ^ ((unsigned)((r & 7) << 4));
        const float v = bf2f(*(const unsigned short*)((const char*)dh[cur] + off))
                      + bf2f(*(const unsigned short*)((const char*)dl[cur] + off));
        out[(size_t)(row0 + r) * N_DIM + j] = v;
    }
}

extern "C" void kernel_launch(void* const* d_in, const int* in_sizes, int n_in,
                              void* d_out, int out_size, void* d_ws, size_t ws_size,
                              hipStream_t stream) {
    const float* y       = (const float*)d_in[0];
    const float* S       = (const float*)d_in[1];
    const float* W       = (const float*)d_in[2];
    const float* thr     = (const float*)d_in[3];
    const int*   numIter = (const int*)d_in[4];
    float* out = (float*)d_out;

    const int Brows = in_sizes[0] / M_DIM;   // 4096
    const int nblk  = Brows / ROWS;          // 256 blocks = 1/CU
    ista_final<<<nblk, NTHREADS, 0, stream>>>(y, S, W, thr, numIter, out);
}